// Round 24
// baseline (139.665 us; speedup 1.0000x reference)
//
#include <hip/hip_runtime.h>

#define BATCH 8
#define SEQ   8192
#define NH    16
#define DP    64
#define ROWF  (NH*DP)        // 1024 floats = 4KB per t (all heads)
#define HGRP  2              // heads per block (512B row slice)
#define NTHR  256            // 4 waves = 2 heads x 2 n-halves
#define KT    32             // t per k-tile = one mfma K-depth
#define RS    260            // dword row-stride (kg-groups 2-way alias = free)

typedef __attribute__((ext_vector_type(8))) short bf16x8;
typedef __attribute__((ext_vector_type(4))) float f32x4;

// round-to-nearest-even f32->bf16 pair pack
static __device__ __forceinline__ unsigned pk2(float lo, float hi) {
    unsigned a = __builtin_bit_cast(unsigned, lo);
    unsigned b = __builtin_bit_cast(unsigned, hi);
    a = (a + 0x7FFFu + ((a >> 16) & 1u)) >> 16;
    b = (b + 0x7FFFu + ((b >> 16) & 1u)) & 0xFFFF0000u;
    return (a & 0xFFFFu) | b;
}

// ---------------------------------------------------------------------------
// k_partial (r23 MFMA structure, 256-thread blocks): per (b,h,chunk):
// C[64p][64n] = sum_t (w*X)[t][p]*B[t][n]  (GEMM, K=t).
// r18-r23: delivery pinned ~5.3 B/cyc/CU with ~1 resident 512-thr block,
// while write-only fill does 27 B/cyc/CU with many blocks/CU. TEST: per-
// block-stream cap vs per-CU cap. 256-thr blocks (2 heads), 19KB LDS ->
// 6-8 blocks/CU by resources, grid 2048 = 8/CU: multiple independent
// phase-pipelines per CU interleave their stalls. t-permutation within the
// K-tile (slot st holds t-pair (w*8+2q+s, +4)) is legal: sum over t is
// order-free; X and B share the mapping; weights applied per-t at pack.
// ---------------------------------------------------------------------------
template<int NBLK>
__global__ __launch_bounds__(NTHR)
void k_partial(const float* __restrict__ Xg, const float* __restrict__ Ag,
               const float* __restrict__ Bg, float* __restrict__ part,
               float* __restrict__ blockA)
{
    constexpr int TB  = SEQ / NBLK;   // 256 (NBLK=32)
    constexpr int Q   = TB / 64;      // 4
    constexpr int NKT = TB / KT;      // 8

    __shared__ unsigned XL[16][RS];   // 16 t-pair slots x 128(+pad) rows
    __shared__ unsigned BL[16][RS];   // (16.6 KB total for both)
    __shared__ float    WT[HGRP][TB]; // 2 KB

    // ---- XCD-gather remap: 8 head-pair blocks of one (b,chunk) -> same XCD
    const int p    = blockIdx.x;            // 0 .. 8*BATCH*NBLK-1 (=2048)
    const int xcd  = p & 7;
    const int q_   = p >> 3;
    const int hgp  = q_ & 7;                // head-pair 0..7
    const int sidx = q_ >> 3;
    const int idx  = sidx * 8 + xcd;        // 0 .. BATCH*NBLK-1
    const int blk  = idx % NBLK;
    const int b    = idx / NBLK;

    const int tid  = threadIdx.x;
    const int w    = tid >> 6;              // 0..3
    const int lane = tid & 63;
    const int hloc = w >> 1;                // head within pair
    const int nh   = w & 1;                 // n-half
    const int h    = hgp * HGRP + hloc;
    const int t0   = blk * TB;

    // ---- per-wave scan of A column h (2 waves/head redo it) ----
    float c[Q];
    {
        const size_t abase = ((size_t)(b * SEQ + t0 + lane * Q)) * NH + h;
        float run = 0.f;
        #pragma unroll
        for (int k = 0; k < Q; ++k) { run += Ag[abase + (size_t)k * NH]; c[k] = run; }
    }
    float tsum = c[Q - 1], s = tsum;
    #pragma unroll
    for (int d = 1; d < 64; d <<= 1) {
        float o = __shfl_up(s, d, 64);
        if (lane >= d) s += o;
    }
    const float total = __shfl(s, 63, 64);
    const float excl  = s - tsum;
    if (nh == 0) {
        #pragma unroll
        for (int k = 0; k < Q; ++k)
            WT[hloc][lane * Q + k] = __expf(total - (excl + c[k]));
        if (lane == 63) blockA[(size_t)(b * NH + h) * NBLK + blk] = total;
    }

    // ---- accumulators: 4 m-tiles x 2 n-tiles of 16x16 ----
    f32x4 acc[4][2];
    #pragma unroll
    for (int mi = 0; mi < 4; ++mi)
        #pragma unroll
        for (int ni = 0; ni < 2; ++ni) acc[mi][ni] = (f32x4){0.f, 0.f, 0.f, 0.f};

    // staging: wave w covers t_locs w*8..w*8+7; load i = rows {2i+side}
    const int side = lane >> 5;              // 0 or 1
    const int l32  = lane & 31;
    const int hw   = l32 >> 4;               // head of this lane's floats
    const size_t gbase = (size_t)(b * SEQ + t0) * ROWF + hgp * (HGRP * DP) + l32 * 4;

    auto issue = [&](int k, float4* lx, float4* lb) {
        if (k >= NKT) return;
        const size_t tb = gbase + (size_t)(k * KT + w * 8 + side) * ROWF;
        #pragma unroll
        for (int i = 0; i < 4; ++i) {
            lx[i] = *(const float4*)(Xg + tb + (size_t)(2 * i) * ROWF);
            lb[i] = *(const float4*)(Bg + tb + (size_t)(2 * i) * ROWF);
        }
    };
    // lane holds t_locs {0,2,4,6}+side+w*8 (loads 0..3); pack pairs (i, i+2):
    // slot st = w*4 + side*2 + q holds t-pair (w*8+2q+side, w*8+2q+side+4)
    auto cwrite = [&](int k, const float4* lx, const float4* lb) {
        #pragma unroll
        for (int q2 = 0; q2 < 2; ++q2) {
            const int tlo = k * KT + w * 8 + 2 * q2 + side;
            const float w0 = WT[hw][tlo];
            const float w1 = WT[hw][tlo + 4];
            const int   st = w * 4 + side * 2 + q2;
            const float* x0 = (const float*)&lx[q2];
            const float* x1 = (const float*)&lx[q2 + 2];
            const float* b0 = (const float*)&lb[q2];
            const float* b1 = (const float*)&lb[q2 + 2];
            uint4 xv, bv;
            xv.x = pk2(x0[0] * w0, x1[0] * w1);
            xv.y = pk2(x0[1] * w0, x1[1] * w1);
            xv.z = pk2(x0[2] * w0, x1[2] * w1);
            xv.w = pk2(x0[3] * w0, x1[3] * w1);
            bv.x = pk2(b0[0], b1[0]);
            bv.y = pk2(b0[1], b1[1]);
            bv.z = pk2(b0[2], b1[2]);
            bv.w = pk2(b0[3], b1[3]);
            *(uint4*)&XL[st][l32 * 4] = xv;        // one ds_write_b128
            *(uint4*)&BL[st][l32 * 4] = bv;
        }
    };
    auto compute = [&]() {
        const int r  = lane & 15;
        const int kg = lane >> 4;
        uint4 af[4], bf[2];
        #pragma unroll
        for (int mi = 0; mi < 4; ++mi) {
            const int row = hloc * 64 + mi * 16 + r;
            af[mi].x = XL[kg * 4 + 0][row];
            af[mi].y = XL[kg * 4 + 1][row];
            af[mi].z = XL[kg * 4 + 2][row];
            af[mi].w = XL[kg * 4 + 3][row];
        }
        #pragma unroll
        for (int ni = 0; ni < 2; ++ni) {
            const int row = hloc * 64 + nh * 32 + ni * 16 + r;
            bf[ni].x = BL[kg * 4 + 0][row];
            bf[ni].y = BL[kg * 4 + 1][row];
            bf[ni].z = BL[kg * 4 + 2][row];
            bf[ni].w = BL[kg * 4 + 3][row];
        }
        #pragma unroll
        for (int mi = 0; mi < 4; ++mi) {
            const bf16x8 a = __builtin_bit_cast(bf16x8, af[mi]);
            #pragma unroll
            for (int ni = 0; ni < 2; ++ni) {
                const bf16x8 bb = __builtin_bit_cast(bf16x8, bf[ni]);
                acc[mi][ni] = __builtin_amdgcn_mfma_f32_16x16x32_bf16(
                                  a, bb, acc[mi][ni], 0, 0, 0);
            }
        }
    };

    // ---- pipeline: 2 reg-sets, single LDS buffer (r18/r23 flow) ----
    float4 sx0[4], sb0[4], sx1[4], sb1[4];
    issue(0, sx0, sb0);
    issue(1, sx1, sb1);
    __syncthreads();                         // WT (and scan) visible

    #pragma unroll 1
    for (int k = 0; k < NKT; k += 2) {
        cwrite(k, sx0, sb0);                 // waits set0's loads
        issue(k + 2, sx0, sb0);
        asm volatile("s_waitcnt lgkmcnt(0)" ::: "memory");
        __builtin_amdgcn_s_barrier();
        __builtin_amdgcn_sched_barrier(0);
        compute();
        __builtin_amdgcn_s_barrier();        // all frag reads done before rewrite

        cwrite(k + 1, sx1, sb1);
        issue(k + 3, sx1, sb1);
        asm volatile("s_waitcnt lgkmcnt(0)" ::: "memory");
        __builtin_amdgcn_s_barrier();
        __builtin_amdgcn_sched_barrier(0);
        compute();
        __builtin_amdgcn_s_barrier();
    }

    // ---- epilogue: C/D layout (m89): col = lane&15, row = (lane>>4)*4 + reg ----
    float* dst = part + ((size_t)(b * NH + h) * NBLK + blk) * 4096;
    {
        const int r  = lane & 15;
        const int cg = lane >> 4;
        #pragma unroll
        for (int mi = 0; mi < 4; ++mi)
            #pragma unroll
            for (int ni = 0; ni < 2; ++ni)
                #pragma unroll
                for (int rr = 0; rr < 4; ++rr)
                    dst[(mi * 16 + cg * 4 + rr) * 64 + nh * 32 + ni * 16 + r] =
                        acc[mi][ni][rr];
    }
}

// ---------------------------------------------------------------------------
// k_combine (scales fused): out[bh,p,n] = sum_c exp(suffixA) * part[bh,c,p,n]
// ---------------------------------------------------------------------------
__global__ __launch_bounds__(256)
void k_combine(const float* __restrict__ part, const float* __restrict__ blockA,
               float* __restrict__ out, int nblk)
{
    const int idx = blockIdx.x * 256 + threadIdx.x;   // 0..524287
    const int bh  = idx >> 12;
    const int e   = idx & 4095;
    float r = 0.f, run = 0.f;
    for (int q = nblk - 1; q >= 0; --q) {             // suffix order
        r   += __expf(run) * part[((size_t)bh * nblk + q) * 4096 + e];
        run += blockA[bh * nblk + q];
    }
    out[idx] = r;
}

// ---------------------------------------------------------------------------
extern "C" void kernel_launch(void* const* d_in, const int* in_sizes, int n_in,
                              void* d_out, int out_size, void* d_ws, size_t ws_size,
                              hipStream_t stream)
{
    const float* X = (const float*)d_in[0];
    const float* A = (const float*)d_in[1];
    const float* B = (const float*)d_in[2];
    float* out     = (float*)d_out;

    const size_t need32 = ((size_t)BATCH * NH * 32 * 4096 + (size_t)BATCH * NH * 32) * 4;
    const int nblk = (ws_size >= need32) ? 32 : 16;

    float* part   = (float*)d_ws;
    float* blockA = part + (size_t)BATCH * NH * nblk * 4096;

    if (nblk == 32)
        hipLaunchKernelGGL((k_partial<32>), dim3(8 * BATCH * 32), dim3(NTHR), 0, stream,
                           X, A, B, part, blockA);
    else
        hipLaunchKernelGGL((k_partial<16>), dim3(8 * BATCH * 16), dim3(NTHR), 0, stream,
                           X, A, B, part, blockA);

    hipLaunchKernelGGL(k_combine, dim3((BATCH * NH * 4096) / 256), dim3(256), 0, stream,
                       part, blockA, out, nblk);
}